// Round 1
// baseline (2429.203 us; speedup 1.0000x reference)
//
#include <hip/hip_runtime.h>
#include <math.h>

#define C 512
#define H 160
#define W 160
#define HW 25600
#define EPS 1e-5f

// ---- workspace float offsets ----
#define OFF_XH      ((size_t)0)         // 81920
#define OFF_XW      ((size_t)81920)     // 81920
#define OFF_SH      ((size_t)163840)    // 81920
#define OFF_SW      ((size_t)245760)    // 81920
#define OFF_CS      ((size_t)327680)    // 512
#define OFF_ALPHA   ((size_t)328192)    // 512
#define OFF_BETA    ((size_t)328704)    // 512
#define OFF_X21     ((size_t)329216)    // 512
#define OFF_X31     ((size_t)329728)    // 512
#define OFF_WEIGHTS ((size_t)330240)    // 25600
#define OFF_WPART   ((size_t)355840)    // 204800
#define OFF_G       ((size_t)560640)    // 262144
#define OFF_GPART   ((size_t)822784)    // 2097152
#define OFF_WT2     ((size_t)2919936)   // 2359296
#define OFF_X2      ((size_t)5279232)   // 13107200
#define OFF_X3      ((size_t)18386432)  // 13107200 -> end 31493632 floats (~126 MB)

__device__ __forceinline__ float sigmoidf_(float v){ return 1.0f/(1.0f+__expf(-v)); }

// K0: wT[kidx][c][o] = w3[o][c][kidx]
__global__ void k0_wT(const float* __restrict__ w3, float* __restrict__ wT){
  int idx = blockIdx.x*256 + threadIdx.x;
  if (idx >= 9*C*C) return;
  int kidx = idx / (C*C);
  int rem  = idx - kidx*(C*C);
  int c = rem / C;
  int o = rem - c*C;
  wT[idx] = w3[(size_t)o*(C*9) + c*9 + kidx];
}

// K1: row means (over W) and col means (over H) per channel
__global__ void k1_means(const float* __restrict__ x, float* __restrict__ xh, float* __restrict__ xw){
  int c = blockIdx.x;
  const float* xc = x + (size_t)c*HW;
  int tid = threadIdx.x;
  int wv = tid >> 6, lane = tid & 63;
  for (int h = wv; h < H; h += 4){
    float s = 0.f;
    for (int w0 = lane; w0 < W; w0 += 64) s += xc[h*W + w0];
    #pragma unroll
    for (int off=32; off; off>>=1) s += __shfl_down(s, off);
    if (lane==0) xh[c*H + h] = s * (1.0f/W);
  }
  if (tid < W){
    float s=0.f;
    for (int h=0;h<H;h++) s += xc[h*W + tid];
    xw[c*W + tid] = s * (1.0f/H);
  }
}

// K2: hw_feat = w1 @ cat + b1, then sigmoid -> sh (C,H), sw (C,W)
__global__ void k2_hwfeat(const float* __restrict__ w1, const float* __restrict__ b1,
                          const float* __restrict__ xh, const float* __restrict__ xw,
                          float* __restrict__ sh, float* __restrict__ sw){
  int o = blockIdx.x;
  int s = threadIdx.x; // 320
  float acc = b1[o];
  const float* w1o = w1 + (size_t)o*C;
  const float* src = (s < H) ? (xh + s) : (xw + (s-H));
  for (int c=0;c<C;c++) acc = fmaf(w1o[c], src[(size_t)c*H], acc); // H==W==160
  float sg = sigmoidf_(acc);
  if (s < H) sh[o*H + s] = sg; else sw[o*W + (s-H)] = sg;
}

// K3: x2 = x * sig_h[c,h] * sig_w[c,w]; chansum[c] = sum over HW of x2
__global__ void k3_x2(const float* __restrict__ x, const float* __restrict__ sh,
                      const float* __restrict__ sw, float* __restrict__ x2,
                      float* __restrict__ chansum){
  int c = blockIdx.x;
  __shared__ float lsh[H];
  __shared__ float lsw[W];
  __shared__ float red[256];
  int tid = threadIdx.x;
  for (int i=tid;i<H;i+=256) lsh[i]=sh[c*H+i];
  for (int i=tid;i<W;i+=256) lsw[i]=sw[c*W+i];
  __syncthreads();
  const float* xc = x + (size_t)c*HW;
  float* x2c = x2 + (size_t)c*HW;
  float s=0.f;
  for (int idx=tid; idx<HW; idx+=256){
    int h = idx/W, w = idx - h*W;
    float v = xc[idx]*lsh[h]*lsw[w];
    x2c[idx]=v; s+=v;
  }
  red[tid]=s; __syncthreads();
  for (int st=128; st; st>>=1){ if (tid<st) red[tid]+=red[tid+st]; __syncthreads(); }
  if (tid==0) chansum[c]=red[0];
}

// K4: conv3x3 as implicit GEMM. out x3[o, s] ; grid (s-tiles=400, o-tiles=8), block 256
__global__ __launch_bounds__(256) void k4_conv(const float* __restrict__ x, const float* __restrict__ wT,
                        const float* __restrict__ b3, float* __restrict__ x3){
  __shared__ float As[16][64];
  __shared__ float Bs[16][64];
  const int tid = threadIdx.x;
  const int tx = tid & 15, ty = tid >> 4;
  const int s_base = blockIdx.x * 64;
  const int o_base = blockIdx.y * 64;
  const int sj = tid & 63, rr = tid >> 6;
  const int s = s_base + sj;
  const int h0 = s / W, w0 = s - h0*W;
  float acc[4][4] = {};
  for (int kidx=0; kidx<9; ++kidx){
    const int hh = h0 + kidx/3 - 1;
    const int ww = w0 + (kidx%3) - 1;
    const bool valid = ((unsigned)hh < (unsigned)H) && ((unsigned)ww < (unsigned)W);
    const float* bsrc = x + ((ptrdiff_t)hh*W + ww);
    const float* asrc = wT + (size_t)kidx*C*C + o_base + sj;
    for (int cb=0; cb<C; cb+=16){
      #pragma unroll
      for (int r=0;r<4;r++){
        int ci = rr + r*4;
        As[ci][sj] = asrc[(size_t)(cb+ci)*C];
        Bs[ci][sj] = valid ? bsrc[(size_t)(cb+ci)*HW] : 0.0f;
      }
      __syncthreads();
      #pragma unroll
      for (int k=0;k<16;k++){
        float4 av = *(const float4*)&As[k][ty*4];
        float4 bv = *(const float4*)&Bs[k][tx*4];
        float a_[4]={av.x,av.y,av.z,av.w};
        float b_[4]={bv.x,bv.y,bv.z,bv.w};
        #pragma unroll
        for(int i2=0;i2<4;i2++)
          #pragma unroll
          for(int j2=0;j2<4;j2++) acc[i2][j2] = fmaf(a_[i2], b_[j2], acc[i2][j2]);
      }
      __syncthreads();
    }
  }
  #pragma unroll
  for (int i2=0;i2<4;i2++){
    int o = o_base + ty*4 + i2;
    float bias = b3[o];
    float4 v = {acc[i2][0]+bias, acc[i2][1]+bias, acc[i2][2]+bias, acc[i2][3]+bias};
    *(float4*)&x3[(size_t)o*HW + s_base + tx*4] = v;
  }
}

// K5: Gram partials: Gpart[z][i][j] = sum over k in z-chunk of x3[i,k]*x3flat[k*C+j]
__global__ __launch_bounds__(256) void k5_gram(const float* __restrict__ x3, float* __restrict__ Gpart){
  __shared__ float As[16][68];
  __shared__ float Bs[16][64];
  const int tid=threadIdx.x;
  const int tx=tid&15, ty=tid>>4;
  const int j_base = blockIdx.x*64;
  const int i_base = blockIdx.y*64;
  const int kz = blockIdx.z*3200;
  const int jj = tid&63, rr=tid>>6;
  const int il = tid>>4, kk=tid&15;
  float acc[4][4]={};
  for (int kb=kz; kb<kz+3200; kb+=16){
    #pragma unroll
    for (int r=0;r<4;r++){
      As[kk][il + 16*r] = x3[(size_t)(i_base + il + 16*r)*HW + kb + kk];
      Bs[rr + 4*r][jj]  = x3[(size_t)(kb + rr + 4*r)*C + j_base + jj];
    }
    __syncthreads();
    #pragma unroll
    for (int k=0;k<16;k++){
      float4 av = *(const float4*)&As[k][ty*4];
      float4 bv = *(const float4*)&Bs[k][tx*4];
      float a_[4]={av.x,av.y,av.z,av.w};
      float b_[4]={bv.x,bv.y,bv.z,bv.w};
      #pragma unroll
      for(int i2=0;i2<4;i2++)
        #pragma unroll
        for(int j2=0;j2<4;j2++) acc[i2][j2] = fmaf(a_[i2], b_[j2], acc[i2][j2]);
    }
    __syncthreads();
  }
  size_t zoff = (size_t)blockIdx.z*C*C;
  #pragma unroll
  for (int i2=0;i2<4;i2++){
    float4 v = {acc[i2][0],acc[i2][1],acc[i2][2],acc[i2][3]};
    *(float4*)&Gpart[zoff + (size_t)(i_base+ty*4+i2)*C + j_base + tx*4] = v;
  }
}

// K5r: reduce 8 partials
__global__ void k5r(const float* __restrict__ Gpart, float* __restrict__ G){
  int idx = blockIdx.x*256 + threadIdx.x;
  float s=0;
  #pragma unroll
  for (int z=0;z<8;z++) s += Gpart[(size_t)z*C*C + idx];
  G[idx]=s;
}

// K5b: per-row GN stats -> alpha, beta
__global__ void k5b(const float* __restrict__ G, const float* __restrict__ gnw, const float* __restrict__ gnb,
                    float* __restrict__ alpha, float* __restrict__ beta){
  int i = blockIdx.x; int tid=threadIdx.x;
  float s=0.f, s2=0.f;
  for (int j=tid;j<C;j+=256){ float v=G[(size_t)i*C+j]; s+=v; s2=fmaf(v,v,s2); }
  __shared__ float r1[4];
  __shared__ float r2[4];
  int lane=tid&63, wv=tid>>6;
  #pragma unroll
  for(int o=32;o;o>>=1){ s+=__shfl_xor(s,o); s2+=__shfl_xor(s2,o); }
  if(lane==0){ r1[wv]=s; r2[wv]=s2; }
  __syncthreads();
  if(tid==0){
    float ss = r1[0]+r1[1]+r1[2]+r1[3];
    float ss2= r2[0]+r2[1]+r2[2]+r2[3];
    float mu = ss/C;
    float var= ss2/C - mu*mu;
    float a  = rsqrtf(var+EPS)*gnw[i];
    alpha[i]=a; beta[i]=gnb[i]-mu*a;
  }
}

__device__ float block_softmax_norm(float v, float* red, int tid){
  int lane=tid&63, wv=tid>>6;
  float m=v;
  #pragma unroll
  for(int o=32;o;o>>=1) m=fmaxf(m,__shfl_xor(m,o));
  if(lane==0) red[wv]=m;
  __syncthreads();
  if(tid==0){ float mm=red[0]; for(int i=1;i<8;i++) mm=fmaxf(mm,red[i]); red[8]=mm; }
  __syncthreads();
  float e=__expf(v-red[8]);
  float su=e;
  #pragma unroll
  for(int o=32;o;o>>=1) su+=__shfl_xor(su,o);
  if(lane==0) red[wv]=su;
  __syncthreads();
  if(tid==0){ float ss=0; for(int i=0;i<8;i++) ss+=red[i]; red[8]=ss; }
  __syncthreads();
  float r = e/red[8];
  __syncthreads();
  return r;
}

// K5c: t[j] = sum_i alpha[i]*G[i,j] + beta[i]; x31 = softmax(t); x21 = softmax(chansum/HW)
__global__ void k5c(const float* __restrict__ G, const float* __restrict__ alpha, const float* __restrict__ beta,
                    const float* __restrict__ chansum, float* __restrict__ x21, float* __restrict__ x31){
  __shared__ float red[9];
  int j = threadIdx.x; // 512
  float t=0.f;
  for (int i=0;i<C;i++) t += alpha[i]*G[(size_t)i*C+j] + beta[i];
  x31[j] = block_softmax_norm(t, red, j);
  float m = chansum[j] * (1.0f/HW);
  x21[j] = block_softmax_norm(m, red, j);
}

// K6: partial weights over c-splits
__global__ void k6_wpart(const float* __restrict__ x2, const float* __restrict__ x3,
                         const float* __restrict__ x21, const float* __restrict__ x31,
                         float* __restrict__ wpart){
  int s = blockIdx.x*256 + threadIdx.x;
  int c0 = blockIdx.y*64;
  float acc=0.f;
  for (int c=c0;c<c0+64;c++){
    acc = fmaf(x21[c], x3[(size_t)c*HW + s], acc);
    acc = fmaf(x31[c], x2[(size_t)c*HW + s], acc);
  }
  wpart[(size_t)blockIdx.y*HW + s] = acc;
}

__global__ void k6r(const float* __restrict__ wpart, float* __restrict__ weights){
  int s = blockIdx.x*256 + threadIdx.x;
  float a=0.f;
  #pragma unroll
  for (int z=0;z<8;z++) a += wpart[(size_t)z*HW + s];
  weights[s]=a;
}

// K7: out = x * sigmoid(weights[s]) (float4)
__global__ void k7_out(const float* __restrict__ x, const float* __restrict__ weights, float* __restrict__ out){
  int idx = blockIdx.x*256 + threadIdx.x; // < C*HW/4
  float4 xv = ((const float4*)x)[idx];
  float4 wv = ((const float4*)weights)[idx % (HW/4)];
  float4 o;
  o.x = xv.x * sigmoidf_(wv.x);
  o.y = xv.y * sigmoidf_(wv.y);
  o.z = xv.z * sigmoidf_(wv.z);
  o.w = xv.w * sigmoidf_(wv.w);
  ((float4*)out)[idx] = o;
}

extern "C" void kernel_launch(void* const* d_in, const int* in_sizes, int n_in,
                              void* d_out, int out_size, void* d_ws, size_t ws_size,
                              hipStream_t stream) {
  const float* x   = (const float*)d_in[0];
  const float* w1  = (const float*)d_in[1];
  const float* b1  = (const float*)d_in[2];
  const float* w3  = (const float*)d_in[3];
  const float* b3  = (const float*)d_in[4];
  const float* gnw = (const float*)d_in[5];
  const float* gnb = (const float*)d_in[6];
  float* out = (float*)d_out;
  float* ws  = (float*)d_ws;

  float* xh      = ws + OFF_XH;
  float* xw      = ws + OFF_XW;
  float* sh      = ws + OFF_SH;
  float* sw      = ws + OFF_SW;
  float* cs      = ws + OFF_CS;
  float* alpha   = ws + OFF_ALPHA;
  float* beta    = ws + OFF_BETA;
  float* x21     = ws + OFF_X21;
  float* x31     = ws + OFF_X31;
  float* weights = ws + OFF_WEIGHTS;
  float* wpart   = ws + OFF_WPART;
  float* G       = ws + OFF_G;
  float* Gpart   = ws + OFF_GPART;
  float* wT2     = ws + OFF_WT2;
  float* x2      = ws + OFF_X2;
  float* x3      = ws + OFF_X3;

  k0_wT   <<<(9*C*C+255)/256, 256, 0, stream>>>(w3, wT2);
  k1_means<<<C, 256, 0, stream>>>(x, xh, xw);
  k2_hwfeat<<<C, 320, 0, stream>>>(w1, b1, xh, xw, sh, sw);
  k3_x2   <<<C, 256, 0, stream>>>(x, sh, sw, x2, cs);
  k4_conv <<<dim3(HW/64, C/64), 256, 0, stream>>>(x, wT2, b3, x3);
  k5_gram <<<dim3(C/64, C/64, 8), 256, 0, stream>>>(x3, Gpart);
  k5r     <<<(C*C)/256, 256, 0, stream>>>(Gpart, G);
  k5b     <<<C, 256, 0, stream>>>(G, gnw, gnb, alpha, beta);
  k5c     <<<1, 512, 0, stream>>>(G, alpha, beta, cs, x21, x31);
  k6_wpart<<<dim3(HW/256, 8), 256, 0, stream>>>(x2, x3, x21, x31, wpart);
  k6r     <<<HW/256, 256, 0, stream>>>(wpart, weights);
  k7_out  <<<(C*HW/4)/256, 256, 0, stream>>>(x, weights, out);
}

// Round 2
// 964.322 us; speedup vs baseline: 2.5191x; 2.5191x over previous
//
#include <hip/hip_runtime.h>
#include <math.h>

#define C 512
#define H 160
#define W 160
#define HW 25600
#define EPS 1e-5f
#define WPAD 168
#define WLDS 164

// ---- workspace float offsets ----
#define OFF_XH      ((size_t)0)         // 81920
#define OFF_XW      ((size_t)81920)     // 81920
#define OFF_SH      ((size_t)163840)    // 81920
#define OFF_SW      ((size_t)245760)    // 81920
#define OFF_CS      ((size_t)327680)    // 512
#define OFF_ALPHA   ((size_t)328192)    // 512
#define OFF_BETA    ((size_t)328704)    // 512
#define OFF_X21     ((size_t)329216)    // 512
#define OFF_X31     ((size_t)329728)    // 512
#define OFF_WEIGHTS ((size_t)330240)    // 25600
#define OFF_WPART   ((size_t)355840)    // 204800
#define OFF_G       ((size_t)560640)    // 262144
#define OFF_GPART   ((size_t)822784)    // 2097152
#define OFF_APH     ((size_t)2919936)   // 1179648 float-slots (2359296 ushort)
#define OFF_APL     ((size_t)4099584)   // 1179648
#define OFF_XPH     ((size_t)5279232)   // 6967296 float-slots (162*168*512 ushort)
#define OFF_XPL     ((size_t)12246528)  // 6967296
#define OFF_X3      ((size_t)19213824)  // 13107200 floats -> end 32321024 (~129 MB)

typedef __attribute__((ext_vector_type(8))) short bf16x8;
typedef __attribute__((ext_vector_type(4))) float f32x4;

__device__ __forceinline__ float sigmoidf_(float v){ return 1.0f/(1.0f+__expf(-v)); }

__device__ __forceinline__ unsigned short f2bf_rne(float f){
  unsigned u = __float_as_uint(f);
  unsigned r = u + 0x7FFFu + ((u>>16)&1u);
  return (unsigned short)(r>>16);
}
__device__ __forceinline__ float bf2f(unsigned short h){ return __uint_as_float(((unsigned)h)<<16); }

// kA: pack w3 into MFMA A-fragment order, split bf16 hi/lo.
// layout: [kidx 9][cb 16][g 4][o 512][i 8], element = w3[o][c=cb*32+g*8+i][kidx]
__global__ void kA_pack(const float* __restrict__ w3, unsigned short* __restrict__ aph,
                        unsigned short* __restrict__ apl){
  int idx = blockIdx.x*256 + threadIdx.x;
  if (idx >= 9*16*4*512*8) return;
  int i = idx & 7, o = (idx>>3)&511, g = (idx>>12)&3, cb = (idx>>14)&15, kidx = idx>>18;
  int c = cb*32 + g*8 + i;
  float v = w3[((size_t)o*C + c)*9 + kidx];
  unsigned short h = f2bf_rne(v);
  unsigned short l = f2bf_rne(v - bf2f(h));
  aph[idx] = h; apl[idx] = l;
}

// kB: x -> padded transposed bf16 hi/lo: xp[hp][wp][c], hp in 0..161, wp in 0..167,
// interior (hp=1..160, wp=1..160) = x[c][hp-1][wp-1], border zero.
__global__ __launch_bounds__(256) void kB_pad(const float* __restrict__ x,
                        unsigned short* __restrict__ xph, unsigned short* __restrict__ xpl){
  int hp = blockIdx.x;        // 0..161
  int c0 = blockIdx.y*64;
  int t = threadIdx.x;
  __shared__ float xs[64][164];
  bool interior = (hp>=1 && hp<=160);
  if (interior){
    int h = hp-1;
    #pragma unroll
    for (int it=0; it<10; ++it){
      int f4 = t + it*256;            // 2560 float4 = 64 rows x 40
      int row = f4/40, col = f4-row*40;
      float4 v = *(const float4*)(x + (size_t)(c0+row)*HW + (size_t)h*W + col*4);
      *(float4*)&xs[row][col*4] = v;
    }
  }
  __syncthreads();
  for (int pass=0; pass<6; ++pass){
    int wp = pass*32 + (t>>3);
    if (wp < WPAD){
      int q = t&7;
      unsigned short hs[8], ls[8];
      if (interior && wp>=1 && wp<=160){
        int w = wp-1;
        #pragma unroll
        for (int j=0;j<8;++j){
          float v = xs[q*8+j][w];
          unsigned short h = f2bf_rne(v);
          hs[j]=h; ls[j]=f2bf_rne(v - bf2f(h));
        }
      } else {
        #pragma unroll
        for (int j=0;j<8;++j){ hs[j]=0; ls[j]=0; }
      }
      size_t off = ((size_t)hp*WPAD + wp)*C + c0 + q*8;
      ushort4 ph0 = {hs[0],hs[1],hs[2],hs[3]}, ph1 = {hs[4],hs[5],hs[6],hs[7]};
      ushort4 pl0 = {ls[0],ls[1],ls[2],ls[3]}, pl1 = {ls[4],ls[5],ls[6],ls[7]};
      *(ushort4*)(xph+off) = ph0; *(ushort4*)(xph+off+4) = ph1;
      *(ushort4*)(xpl+off) = pl0; *(ushort4*)(xpl+off+4) = pl1;
    }
  }
}

// K1: row means (over W) and col means (over H) per channel
__global__ void k1_means(const float* __restrict__ x, float* __restrict__ xh, float* __restrict__ xw){
  int c = blockIdx.x;
  const float* xc = x + (size_t)c*HW;
  int tid = threadIdx.x;
  int wv = tid >> 6, lane = tid & 63;
  for (int h = wv; h < H; h += 4){
    float s = 0.f;
    for (int w0 = lane; w0 < W; w0 += 64) s += xc[h*W + w0];
    #pragma unroll
    for (int off=32; off; off>>=1) s += __shfl_down(s, off);
    if (lane==0) xh[c*H + h] = s * (1.0f/W);
  }
  if (tid < W){
    float s=0.f;
    for (int h=0;h<H;h++) s += xc[h*W + tid];
    xw[c*W + tid] = s * (1.0f/H);
  }
}

// K2: hw_feat = w1 @ cat + b1, then sigmoid -> sh (C,H), sw (C,W)
__global__ void k2_hwfeat(const float* __restrict__ w1, const float* __restrict__ b1,
                          const float* __restrict__ xh, const float* __restrict__ xw,
                          float* __restrict__ sh, float* __restrict__ sw){
  int o = blockIdx.x;
  int s = threadIdx.x; // 320
  float acc = b1[o];
  const float* w1o = w1 + (size_t)o*C;
  const float* src = (s < H) ? (xh + s) : (xw + (s-H));
  for (int c=0;c<C;c++) acc = fmaf(w1o[c], src[(size_t)c*H], acc); // H==W==160
  float sg = sigmoidf_(acc);
  if (s < H) sh[o*H + s] = sg; else sw[o*W + (s-H)] = sg;
}

// K3: chansum[c] = sum over HW of x*sig_h*sig_w (x2 not materialized)
__global__ void k3_cs(const float* __restrict__ x, const float* __restrict__ sh,
                      const float* __restrict__ sw, float* __restrict__ chansum){
  int c = blockIdx.x;
  __shared__ float lsh[H];
  __shared__ float lsw[W];
  __shared__ float red[256];
  int tid = threadIdx.x;
  for (int i=tid;i<H;i+=256) lsh[i]=sh[c*H+i];
  for (int i=tid;i<W;i+=256) lsw[i]=sw[c*W+i];
  __syncthreads();
  const float* xc = x + (size_t)c*HW;
  float s=0.f;
  for (int idx=tid; idx<HW; idx+=256){
    int h = idx/W, w = idx - h*W;
    s += xc[idx]*lsh[h]*lsw[w];
  }
  red[tid]=s; __syncthreads();
  for (int st=128; st; st>>=1){ if (tid<st) red[tid]+=red[tid+st]; __syncthreads(); }
  if (tid==0) chansum[c]=red[0];
}

// K4: conv3x3 via bf16x3 MFMA implicit GEMM.
// Block: 256 thr (4 waves 2m x 2n), tile 128(o) x 160(s=one output row), BK=32 c.
__global__ __launch_bounds__(256) void k4_mfma(const unsigned short* __restrict__ xph,
                        const unsigned short* __restrict__ xpl,
                        const unsigned short* __restrict__ aph,
                        const unsigned short* __restrict__ apl,
                        const float* __restrict__ b3, float* __restrict__ x3){
  __shared__ unsigned short Bst[3*2*WLDS*32]; // [dh][part][wp<164][c32] = 63KB
  const int h0 = blockIdx.x;
  const int o_base = blockIdx.y*128;
  const int tid = threadIdx.x;
  const int lane = tid & 63;
  const int wave = tid >> 6;
  const int wm = wave & 1, wn = wave >> 1;
  const int ln = lane & 15, g = lane >> 4;
  const int o_wave = o_base + wm*64 + ln;
  const int wbase = wn*80 + ln;

  f32x4 acc[4][5] = {};

  for (int cb=0; cb<16; ++cb){
    const int c0 = cb*32;
    __syncthreads();
    // stage 3 padded rows (h0..h0+2) x 32 c, hi+lo
    for (int dh=0; dh<3; ++dh){
      const size_t gbase = ((size_t)(h0+dh)*WPAD)*C + c0;
      #pragma unroll
      for (int part=0; part<2; ++part){
        const unsigned short* src = part ? xpl : xph;
        unsigned short* dst = &Bst[(dh*2+part)*WLDS*32];
        for (int slot = tid; slot < WLDS*4; slot += 256){
          int wp = slot >> 2, q = slot & 3;
          float4 v = *(const float4*)(src + gbase + (size_t)wp*C + q*8);
          *(float4*)(dst + slot*8) = v;
        }
      }
    }
    __syncthreads();
    for (int dh=0; dh<3; ++dh){
      #pragma unroll
      for (int dw=0; dw<3; ++dw){
        const int kidx = dh*3+dw;
        const size_t ab = (size_t)((kidx*16 + cb)*4 + g)*4096 + (size_t)o_wave*8;
        bf16x8 ah[4], al[4];
        #pragma unroll
        for (int fm=0; fm<4; ++fm){
          ah[fm] = *(const bf16x8*)(aph + ab + fm*128);
          al[fm] = *(const bf16x8*)(apl + ab + fm*128);
        }
        #pragma unroll
        for (int fn=0; fn<5; ++fn){
          const int wp = wbase + fn*16 + dw;
          bf16x8 bh = *(const bf16x8*)&Bst[((dh*2+0)*WLDS + wp)*32 + g*8];
          bf16x8 bl = *(const bf16x8*)&Bst[((dh*2+1)*WLDS + wp)*32 + g*8];
          #pragma unroll
          for (int fm=0; fm<4; ++fm){
            acc[fm][fn] = __builtin_amdgcn_mfma_f32_16x16x32_bf16(ah[fm], bh, acc[fm][fn],0,0,0);
            acc[fm][fn] = __builtin_amdgcn_mfma_f32_16x16x32_bf16(ah[fm], bl, acc[fm][fn],0,0,0);
            acc[fm][fn] = __builtin_amdgcn_mfma_f32_16x16x32_bf16(al[fm], bh, acc[fm][fn],0,0,0);
          }
        }
      }
    }
  }
  // epilogue: D frag col=lane&15 (w), row=g*4+r (o)
  #pragma unroll
  for (int fm=0; fm<4; ++fm){
    #pragma unroll
    for (int r=0; r<4; ++r){
      const int oo = o_base + wm*64 + fm*16 + g*4 + r;
      const float bias = b3[oo];
      float* dst = x3 + (size_t)oo*HW + (size_t)h0*W;
      #pragma unroll
      for (int fn=0; fn<5; ++fn){
        dst[wn*80 + fn*16 + ln] = acc[fm][fn][r] + bias;
      }
    }
  }
}

// K5: Gram partials (fp32): Gpart[z][i][j] = sum over k-chunk of x3[i,k]*x3flat[k*C+j]
__global__ __launch_bounds__(256) void k5_gram(const float* __restrict__ x3, float* __restrict__ Gpart){
  __shared__ float As[16][68];
  __shared__ float Bs[16][64];
  const int tid=threadIdx.x;
  const int tx=tid&15, ty=tid>>4;
  const int j_base = blockIdx.x*64;
  const int i_base = blockIdx.y*64;
  const int kz = blockIdx.z*3200;
  const int jj = tid&63, rr=tid>>6;
  const int il = tid>>4, kk=tid&15;
  float acc[4][4]={};
  for (int kb=kz; kb<kz+3200; kb+=16){
    #pragma unroll
    for (int r=0;r<4;r++){
      As[kk][il + 16*r] = x3[(size_t)(i_base + il + 16*r)*HW + kb + kk];
      Bs[rr + 4*r][jj]  = x3[(size_t)(kb + rr + 4*r)*C + j_base + jj];
    }
    __syncthreads();
    #pragma unroll
    for (int k=0;k<16;k++){
      float4 av = *(const float4*)&As[k][ty*4];
      float4 bv = *(const float4*)&Bs[k][tx*4];
      float a_[4]={av.x,av.y,av.z,av.w};
      float b_[4]={bv.x,bv.y,bv.z,bv.w};
      #pragma unroll
      for(int i2=0;i2<4;i2++)
        #pragma unroll
        for(int j2=0;j2<4;j2++) acc[i2][j2] = fmaf(a_[i2], b_[j2], acc[i2][j2]);
    }
    __syncthreads();
  }
  size_t zoff = (size_t)blockIdx.z*C*C;
  #pragma unroll
  for (int i2=0;i2<4;i2++){
    float4 v = {acc[i2][0],acc[i2][1],acc[i2][2],acc[i2][3]};
    *(float4*)&Gpart[zoff + (size_t)(i_base+ty*4+i2)*C + j_base + tx*4] = v;
  }
}

__global__ void k5r(const float* __restrict__ Gpart, float* __restrict__ G){
  int idx = blockIdx.x*256 + threadIdx.x;
  float s=0;
  #pragma unroll
  for (int z=0;z<8;z++) s += Gpart[(size_t)z*C*C + idx];
  G[idx]=s;
}

__global__ void k5b(const float* __restrict__ G, const float* __restrict__ gnw, const float* __restrict__ gnb,
                    float* __restrict__ alpha, float* __restrict__ beta){
  int i = blockIdx.x; int tid=threadIdx.x;
  float s=0.f, s2=0.f;
  for (int j=tid;j<C;j+=256){ float v=G[(size_t)i*C+j]; s+=v; s2=fmaf(v,v,s2); }
  __shared__ float r1[4];
  __shared__ float r2[4];
  int lane=tid&63, wv=tid>>6;
  #pragma unroll
  for(int o=32;o;o>>=1){ s+=__shfl_xor(s,o); s2+=__shfl_xor(s2,o); }
  if(lane==0){ r1[wv]=s; r2[wv]=s2; }
  __syncthreads();
  if(tid==0){
    float ss = r1[0]+r1[1]+r1[2]+r1[3];
    float ss2= r2[0]+r2[1]+r2[2]+r2[3];
    float mu = ss/C;
    float var= ss2/C - mu*mu;
    float a  = rsqrtf(var+EPS)*gnw[i];
    alpha[i]=a; beta[i]=gnb[i]-mu*a;
  }
}

__device__ float block_softmax_norm(float v, float* red, int tid){
  int lane=tid&63, wv=tid>>6;
  float m=v;
  #pragma unroll
  for(int o=32;o;o>>=1) m=fmaxf(m,__shfl_xor(m,o));
  if(lane==0) red[wv]=m;
  __syncthreads();
  if(tid==0){ float mm=red[0]; for(int i=1;i<8;i++) mm=fmaxf(mm,red[i]); red[8]=mm; }
  __syncthreads();
  float e=__expf(v-red[8]);
  float su=e;
  #pragma unroll
  for(int o=32;o;o>>=1) su+=__shfl_xor(su,o);
  if(lane==0) red[wv]=su;
  __syncthreads();
  if(tid==0){ float ss=0; for(int i=0;i<8;i++) ss+=red[i]; red[8]=ss; }
  __syncthreads();
  float r = e/red[8];
  __syncthreads();
  return r;
}

__global__ void k5c(const float* __restrict__ G, const float* __restrict__ alpha, const float* __restrict__ beta,
                    const float* __restrict__ chansum, float* __restrict__ x21, float* __restrict__ x31){
  __shared__ float red[9];
  int j = threadIdx.x; // 512
  float t=0.f;
  for (int i=0;i<C;i++) t += alpha[i]*G[(size_t)i*C+j] + beta[i];
  x31[j] = block_softmax_norm(t, red, j);
  float m = chansum[j] * (1.0f/HW);
  x21[j] = block_softmax_norm(m, red, j);
}

// K6: partial weights; x2 recomputed inline from x * sh * sw
__global__ void k6_wpart(const float* __restrict__ x, const float* __restrict__ x3,
                         const float* __restrict__ sh, const float* __restrict__ sw,
                         const float* __restrict__ x21, const float* __restrict__ x31,
                         float* __restrict__ wpart){
  int s = blockIdx.x*256 + threadIdx.x;
  int h = s/W, w = s - h*W;
  int c0 = blockIdx.y*64;
  float acc=0.f;
  for (int c=c0;c<c0+64;c++){
    float xv = x[(size_t)c*HW + s];
    float x2v = xv * sh[c*H + h] * sw[c*W + w];
    acc = fmaf(x21[c], x3[(size_t)c*HW + s], acc);
    acc = fmaf(x31[c], x2v, acc);
  }
  wpart[(size_t)blockIdx.y*HW + s] = acc;
}

__global__ void k6r(const float* __restrict__ wpart, float* __restrict__ weights){
  int s = blockIdx.x*256 + threadIdx.x;
  float a=0.f;
  #pragma unroll
  for (int z=0;z<8;z++) a += wpart[(size_t)z*HW + s];
  weights[s]=a;
}

__global__ void k7_out(const float* __restrict__ x, const float* __restrict__ weights, float* __restrict__ out){
  int idx = blockIdx.x*256 + threadIdx.x; // < C*HW/4
  float4 xv = ((const float4*)x)[idx];
  float4 wv = ((const float4*)weights)[idx % (HW/4)];
  float4 o;
  o.x = xv.x * sigmoidf_(wv.x);
  o.y = xv.y * sigmoidf_(wv.y);
  o.z = xv.z * sigmoidf_(wv.z);
  o.w = xv.w * sigmoidf_(wv.w);
  ((float4*)out)[idx] = o;
}

extern "C" void kernel_launch(void* const* d_in, const int* in_sizes, int n_in,
                              void* d_out, int out_size, void* d_ws, size_t ws_size,
                              hipStream_t stream) {
  const float* x   = (const float*)d_in[0];
  const float* w1  = (const float*)d_in[1];
  const float* b1  = (const float*)d_in[2];
  const float* w3  = (const float*)d_in[3];
  const float* b3  = (const float*)d_in[4];
  const float* gnw = (const float*)d_in[5];
  const float* gnb = (const float*)d_in[6];
  float* out = (float*)d_out;
  float* ws  = (float*)d_ws;

  float* xh      = ws + OFF_XH;
  float* xw      = ws + OFF_XW;
  float* sh      = ws + OFF_SH;
  float* sw      = ws + OFF_SW;
  float* cs      = ws + OFF_CS;
  float* alpha   = ws + OFF_ALPHA;
  float* beta    = ws + OFF_BETA;
  float* x21     = ws + OFF_X21;
  float* x31     = ws + OFF_X31;
  float* weights = ws + OFF_WEIGHTS;
  float* wpart   = ws + OFF_WPART;
  float* G       = ws + OFF_G;
  float* Gpart   = ws + OFF_GPART;
  unsigned short* aph = (unsigned short*)(ws + OFF_APH);
  unsigned short* apl = (unsigned short*)(ws + OFF_APL);
  unsigned short* xph = (unsigned short*)(ws + OFF_XPH);
  unsigned short* xpl = (unsigned short*)(ws + OFF_XPL);
  float* x3      = ws + OFF_X3;

  kA_pack <<<(9*16*4*512*8 + 255)/256, 256, 0, stream>>>(w3, aph, apl);
  kB_pad  <<<dim3(162, 8), 256, 0, stream>>>(x, xph, xpl);
  k1_means<<<C, 256, 0, stream>>>(x, xh, xw);
  k2_hwfeat<<<C, 320, 0, stream>>>(w1, b1, xh, xw, sh, sw);
  k3_cs   <<<C, 256, 0, stream>>>(x, sh, sw, cs);
  k4_mfma <<<dim3(H, 4), 256, 0, stream>>>(xph, xpl, aph, apl, b3, x3);
  k5_gram <<<dim3(C/64, C/64, 8), 256, 0, stream>>>(x3, Gpart);
  k5r     <<<(C*C)/256, 256, 0, stream>>>(Gpart, G);
  k5b     <<<C, 256, 0, stream>>>(G, gnw, gnb, alpha, beta);
  k5c     <<<1, 512, 0, stream>>>(G, alpha, beta, cs, x21, x31);
  k6_wpart<<<dim3(HW/256, 8), 256, 0, stream>>>(x, x3, sh, sw, x21, x31, wpart);
  k6r     <<<HW/256, 256, 0, stream>>>(wpart, weights);
  k7_out  <<<(C*HW/4)/256, 256, 0, stream>>>(x, weights, out);
}

// Round 6
// 766.099 us; speedup vs baseline: 3.1709x; 1.2587x over previous
//
#include <hip/hip_runtime.h>
#include <math.h>

#define C 512
#define H 160
#define W 160
#define HW 25600
#define EPS 1e-5f
#define WPAD 168

// ---- workspace float offsets ----
#define OFF_XH      ((size_t)0)         // 81920
#define OFF_XW      ((size_t)81920)     // 81920
#define OFF_SH      ((size_t)163840)    // 81920
#define OFF_SW      ((size_t)245760)    // 81920
#define OFF_CS      ((size_t)327680)    // 512
#define OFF_ALPHA   ((size_t)328192)    // 512
#define OFF_BETA    ((size_t)328704)    // 512
#define OFF_X21     ((size_t)329216)    // 512
#define OFF_X31     ((size_t)329728)    // 512
#define OFF_WEIGHTS ((size_t)330240)    // 25600
#define OFF_G       ((size_t)355840)    // 262144
#define OFF_WPART   ((size_t)617984)    // 204800
#define OFF_X3      ((size_t)822784)    // 13107200 -> end 13929984
#define OFF_R       ((size_t)13929984)  // overlay region, 16293888 floats -> end 30223872 (~121MB)

typedef __attribute__((ext_vector_type(8))) short bf16x8;
typedef __attribute__((ext_vector_type(8))) unsigned short u16x8;
typedef __attribute__((ext_vector_type(4))) float f32x4;

__device__ __forceinline__ float sigmoidf_(float v){ return 1.0f/(1.0f+__expf(-v)); }

__device__ __forceinline__ unsigned short f2bf_rne(float f){
  unsigned u = __float_as_uint(f);
  unsigned r = u + 0x7FFFu + ((u>>16)&1u);
  return (unsigned short)(r>>16);
}
__device__ __forceinline__ float bf2f(unsigned short h){ return __uint_as_float(((unsigned)h)<<16); }

// kA: pack w3 into MFMA A-fragment order, split bf16 hi/lo.
// layout: [kidx 9][cb 16][g 4][o 512][i 8], element = w3[o][c=cb*32+g*8+i][kidx]
__global__ void kA_pack(const float* __restrict__ w3, unsigned short* __restrict__ aph,
                        unsigned short* __restrict__ apl){
  int idx = blockIdx.x*256 + threadIdx.x;
  if (idx >= 9*16*4*512*8) return;
  int i = idx & 7, o = (idx>>3)&511, g = (idx>>12)&3, cb = (idx>>14)&15, kidx = idx>>18;
  int c = cb*32 + g*8 + i;
  float v = w3[((size_t)o*C + c)*9 + kidx];
  unsigned short h = f2bf_rne(v);
  unsigned short l = f2bf_rne(v - bf2f(h));
  aph[idx] = h; apl[idx] = l;
}

// kB: x -> padded transposed bf16 hi/lo: xp[hp][wp][c]
__global__ __launch_bounds__(256) void kB_pad(const float* __restrict__ x,
                        unsigned short* __restrict__ xph, unsigned short* __restrict__ xpl){
  int hp = blockIdx.x;        // 0..161
  int c0 = blockIdx.y*64;
  int t = threadIdx.x;
  __shared__ float xs[64][164];
  bool interior = (hp>=1 && hp<=160);
  if (interior){
    int h = hp-1;
    #pragma unroll
    for (int it=0; it<10; ++it){
      int f4 = t + it*256;            // 2560 float4 = 64 rows x 40
      int row = f4/40, col = f4-row*40;
      float4 v = *(const float4*)(x + (size_t)(c0+row)*HW + (size_t)h*W + col*4);
      *(float4*)&xs[row][col*4] = v;
    }
  }
  __syncthreads();
  for (int pass=0; pass<6; ++pass){
    int wp = pass*32 + (t>>3);
    if (wp < WPAD){
      int q = t&7;
      unsigned short hs[8], ls[8];
      if (interior && wp>=1 && wp<=160){
        int w = wp-1;
        #pragma unroll
        for (int j=0;j<8;++j){
          float v = xs[q*8+j][w];
          unsigned short h = f2bf_rne(v);
          hs[j]=h; ls[j]=f2bf_rne(v - bf2f(h));
        }
      } else {
        #pragma unroll
        for (int j=0;j<8;++j){ hs[j]=0; ls[j]=0; }
      }
      size_t off = ((size_t)hp*WPAD + wp)*C + c0 + q*8;
      ushort4 ph0 = {hs[0],hs[1],hs[2],hs[3]}, ph1 = {hs[4],hs[5],hs[6],hs[7]};
      ushort4 pl0 = {ls[0],ls[1],ls[2],ls[3]}, pl1 = {ls[4],ls[5],ls[6],ls[7]};
      *(ushort4*)(xph+off) = ph0; *(ushort4*)(xph+off+4) = ph1;
      *(ushort4*)(xpl+off) = pl0; *(ushort4*)(xpl+off+4) = pl1;
    }
  }
}

// K1: row means (over W) and col means (over H) per channel
__global__ void k1_means(const float* __restrict__ x, float* __restrict__ xh, float* __restrict__ xw){
  int c = blockIdx.x;
  const float* xc = x + (size_t)c*HW;
  int tid = threadIdx.x;
  int wv = tid >> 6, lane = tid & 63;
  for (int h = wv; h < H; h += 4){
    float s = 0.f;
    for (int w0 = lane; w0 < W; w0 += 64) s += xc[h*W + w0];
    #pragma unroll
    for (int off=32; off; off>>=1) s += __shfl_down(s, off);
    if (lane==0) xh[c*H + h] = s * (1.0f/W);
  }
  if (tid < W){
    float s=0.f;
    for (int h=0;h<H;h++) s += xc[h*W + tid];
    xw[c*W + tid] = s * (1.0f/H);
  }
}

// K2: hw_feat = w1 @ cat + b1, then sigmoid -> sh (C,H), sw (C,W)
__global__ void k2_hwfeat(const float* __restrict__ w1, const float* __restrict__ b1,
                          const float* __restrict__ xh, const float* __restrict__ xw,
                          float* __restrict__ sh, float* __restrict__ sw){
  int o = blockIdx.x;
  int s = threadIdx.x; // 320
  float acc = b1[o];
  const float* w1o = w1 + (size_t)o*C;
  const float* src = (s < H) ? (xh + s) : (xw + (s-H));
  for (int c=0;c<C;c++) acc = fmaf(w1o[c], src[(size_t)c*H], acc);
  float sg = sigmoidf_(acc);
  if (s < H) sh[o*H + s] = sg; else sw[o*W + (s-H)] = sg;
}

// K3: chansum[c] = sum over HW of x*sig_h*sig_w
__global__ void k3_cs(const float* __restrict__ x, const float* __restrict__ sh,
                      const float* __restrict__ sw, float* __restrict__ chansum){
  int c = blockIdx.x;
  __shared__ float lsh[H];
  __shared__ float lsw[W];
  __shared__ float red[256];
  int tid = threadIdx.x;
  for (int i=tid;i<H;i+=256) lsh[i]=sh[c*H+i];
  for (int i=tid;i<W;i+=256) lsw[i]=sw[c*W+i];
  __syncthreads();
  const float* xc = x + (size_t)c*HW;
  float s=0.f;
  for (int idx=tid; idx<HW; idx+=256){
    int h = idx/W, w = idx - h*W;
    s += xc[idx]*lsh[h]*lsw[w];
  }
  red[tid]=s; __syncthreads();
  for (int st=128; st; st>>=1){ if (tid<st) red[tid]+=red[tid+st]; __syncthreads(); }
  if (tid==0) chansum[c]=red[0];
}

// K4 v3: conv3x3 bf16x3 MFMA. tile 256(o) x 80(s), BK=32. 4 waves each 64o x 80s.
// LDS 32.25KB -> 4 blocks/CU. XOR-swizzled LDS slots, register-preloaded fragments.
__global__ __launch_bounds__(256) void k4_mfma(const unsigned short* __restrict__ xph,
                        const unsigned short* __restrict__ xpl,
                        const unsigned short* __restrict__ aph,
                        const unsigned short* __restrict__ apl,
                        const float* __restrict__ b3, float* __restrict__ x3){
  __shared__ unsigned short Bst[6*84*32]; // [dh*2+part][wl 84][c 32] = 32256 B
  int raw = blockIdx.x;                   // 640, XCD-bijective swizzle (640%8==0)
  int id  = (raw & 7)*80 + (raw >> 3);
  int sx  = id % 320;
  int o_base = (id / 320) * 256;
  int h0 = sx >> 1, half = sx & 1;
  int wp0 = half * 80;
  const int tid = threadIdx.x, lane = tid & 63, w = tid >> 6;
  const int ln = lane & 15, g = lane >> 4;
  const int o_w = o_base + w*64;

  f32x4 acc[4][5] = {};

  for (int cb = 0; cb < 16; ++cb){
    const int c0 = cb*32;
    __syncthreads();
    #pragma unroll
    for (int dh = 0; dh < 3; ++dh){
      const size_t gbase = ((size_t)(h0+dh)*WPAD + wp0)*C + c0;
      #pragma unroll
      for (int part = 0; part < 2; ++part){
        const unsigned short* src = part ? xpl : xph;
        unsigned short* dst = &Bst[(dh*2+part)*84*32];
        #pragma unroll
        for (int it = 0; it < 2; ++it){
          int slot = tid + it*256;
          if (slot < 336){
            int wl = slot >> 2, q = slot & 3;
            float4 v = *(const float4*)(src + gbase + (size_t)wl*C + q*8);
            *(float4*)(dst + wl*32 + ((q ^ ((wl>>1)&3))*8)) = v;
          }
        }
      }
    }
    __syncthreads();
    #pragma unroll
    for (int dh = 0; dh < 3; ++dh){
      #pragma unroll
      for (int dw = 0; dw < 3; ++dw){
        const int kidx = dh*3 + dw;
        const size_t ab = (size_t)((kidx*16 + cb)*4 + g)*4096 + (size_t)(o_w + ln)*8;
        bf16x8 ah[4], al[4];
        #pragma unroll
        for (int fm = 0; fm < 4; ++fm){
          ah[fm] = *(const bf16x8*)(aph + ab + fm*128);
          al[fm] = *(const bf16x8*)(apl + ab + fm*128);
        }
        bf16x8 bh[5], bl[5];
        #pragma unroll
        for (int fn = 0; fn < 5; ++fn){
          int wl = fn*16 + ln + dw;
          int ss = (g ^ ((wl>>1)&3))*8;
          bh[fn] = *(const bf16x8*)&Bst[((dh*2+0)*84 + wl)*32 + ss];
          bl[fn] = *(const bf16x8*)&Bst[((dh*2+1)*84 + wl)*32 + ss];
        }
        #pragma unroll
        for (int fn = 0; fn < 5; ++fn)
          #pragma unroll
          for (int fm = 0; fm < 4; ++fm){
            acc[fm][fn] = __builtin_amdgcn_mfma_f32_16x16x32_bf16(ah[fm], bh[fn], acc[fm][fn],0,0,0);
            acc[fm][fn] = __builtin_amdgcn_mfma_f32_16x16x32_bf16(ah[fm], bl[fn], acc[fm][fn],0,0,0);
            acc[fm][fn] = __builtin_amdgcn_mfma_f32_16x16x32_bf16(al[fm], bh[fn], acc[fm][fn],0,0,0);
          }
      }
    }
  }
  #pragma unroll
  for (int fm = 0; fm < 4; ++fm){
    #pragma unroll
    for (int r = 0; r < 4; ++r){
      const int oo = o_w + fm*16 + g*4 + r;
      const float bias = b3[oo];
      float* dst = x3 + (size_t)oo*HW + (size_t)h0*W + wp0;
      #pragma unroll
      for (int fn = 0; fn < 5; ++fn) dst[fn*16 + ln] = acc[fm][fn][r] + bias;
    }
  }
}

// kT: Bt[j][k] = bf16split(x3flat[k*C+j]); j<512, k<25600. 64x64 LDS transpose tiles.
__global__ __launch_bounds__(256) void kT_trans(const float* __restrict__ x3,
                        unsigned short* __restrict__ Bth, unsigned short* __restrict__ Btl){
  __shared__ float tile[64][65];
  const int k0 = blockIdx.x*64, j0 = blockIdx.y*64;
  const int t = threadIdx.x;
  #pragma unroll
  for (int it=0; it<4; ++it){
    int kl = it*16 + (t>>4);
    int jl = (t&15)*4;
    float4 v = *(const float4*)(x3 + (size_t)(k0+kl)*C + j0 + jl);
    tile[kl][jl]=v.x; tile[kl][jl+1]=v.y; tile[kl][jl+2]=v.z; tile[kl][jl+3]=v.w;
  }
  __syncthreads();
  #pragma unroll
  for (int it=0; it<4; ++it){
    int jl = it*16 + (t>>4);
    int kq = t&15;
    unsigned short hs[4], ls[4];
    #pragma unroll
    for (int d=0; d<4; ++d){
      float v = tile[kq*4+d][jl];
      unsigned short h = f2bf_rne(v);
      hs[d]=h; ls[d]=f2bf_rne(v - bf2f(h));
    }
    size_t off = (size_t)(j0+jl)*HW + k0 + kq*4;
    ushort4 vh = {hs[0],hs[1],hs[2],hs[3]};
    ushort4 vl = {ls[0],ls[1],ls[2],ls[3]};
    *(ushort4*)(Bth+off) = vh;
    *(ushort4*)(Btl+off) = vl;
  }
}

// kz: zero G
__global__ void kz_zero(float* __restrict__ G){
  G[blockIdx.x*256 + threadIdx.x] = 0.f;
}

// k5g: Gram via bf16x3 MFMA. tile 128x128, z=16 K-split, atomicAdd into G.
__global__ __launch_bounds__(256) void k5g(const float* __restrict__ x3,
                        const unsigned short* __restrict__ Bth,
                        const unsigned short* __restrict__ Btl,
                        float* __restrict__ G){
  __shared__ unsigned short Ah[128*32], Al[128*32], Bh[128*32], Bl[128*32]; // 32KB
  const int j0 = blockIdx.x * 128;
  const int i0 = blockIdx.y * 128;
  const int kz = blockIdx.z * 1600;
  const int tid = threadIdx.x, lane = tid & 63, w = tid >> 6;
  const int ln = lane & 15, g = lane >> 4;
  const int wi = w & 1, wj = w >> 1;
  f32x4 acc[4][4] = {};
  for (int kb = 0; kb < 1600; kb += 32){
    const int kk = kz + kb;
    __syncthreads();
    #pragma unroll
    for (int it = 0; it < 2; ++it){
      int slot = tid + it*256;      // 512 slots: 128 rows x 4 q
      int il = slot >> 2, q = slot & 3;
      int ss = (q ^ ((il>>1)&3))*8;
      const float* asrc = x3 + (size_t)(i0+il)*HW + kk + q*8;
      float4 a0 = *(const float4*)asrc;
      float4 a1 = *(const float4*)(asrc+4);
      float av[8] = {a0.x,a0.y,a0.z,a0.w,a1.x,a1.y,a1.z,a1.w};
      u16x8 vh, vl;
      #pragma unroll
      for (int e=0;e<8;++e){
        unsigned short h = f2bf_rne(av[e]);
        vh[e]=h; vl[e]=f2bf_rne(av[e]-bf2f(h));
      }
      *(u16x8*)&Ah[il*32+ss] = vh;
      *(u16x8*)&Al[il*32+ss] = vl;
      size_t boff = (size_t)(j0+il)*HW + kk + q*8;
      *(u16x8*)&Bh[il*32+ss] = *(const u16x8*)(Bth + boff);
      *(u16x8*)&Bl[il*32+ss] = *(const u16x8*)(Btl + boff);
    }
    __syncthreads();
    bf16x8 bfh[4], bfl[4];
    #pragma unroll
    for (int fj=0; fj<4; ++fj){
      int jl = wj*64 + fj*16 + ln;
      int ss = (g ^ ((jl>>1)&3))*8;
      bfh[fj] = *(const bf16x8*)&Bh[jl*32+ss];
      bfl[fj] = *(const bf16x8*)&Bl[jl*32+ss];
    }
    #pragma unroll
    for (int fi=0; fi<4; ++fi){
      int il = wi*64 + fi*16 + ln;
      int ss = (g ^ ((il>>1)&3))*8;
      bf16x8 afh = *(const bf16x8*)&Ah[il*32+ss];
      bf16x8 afl = *(const bf16x8*)&Al[il*32+ss];
      #pragma unroll
      for (int fj=0; fj<4; ++fj){
        acc[fi][fj] = __builtin_amdgcn_mfma_f32_16x16x32_bf16(afh, bfh[fj], acc[fi][fj],0,0,0);
        acc[fi][fj] = __builtin_amdgcn_mfma_f32_16x16x32_bf16(afh, bfl[fj], acc[fi][fj],0,0,0);
        acc[fi][fj] = __builtin_amdgcn_mfma_f32_16x16x32_bf16(afl, bfh[fj], acc[fi][fj],0,0,0);
      }
    }
  }
  #pragma unroll
  for (int fi=0; fi<4; ++fi)
    #pragma unroll
    for (int fj=0; fj<4; ++fj)
      #pragma unroll
      for (int r=0; r<4; ++r){
        int ii = i0 + wi*64 + fi*16 + g*4 + r;
        int jj = j0 + wj*64 + fj*16 + ln;
        atomicAdd(&G[(size_t)ii*C + jj], acc[fi][fj][r]);
      }
}

// k5b: per-row GN stats -> alpha, beta
__global__ void k5b(const float* __restrict__ G, const float* __restrict__ gnw, const float* __restrict__ gnb,
                    float* __restrict__ alpha, float* __restrict__ beta){
  int i = blockIdx.x; int tid=threadIdx.x;
  float s=0.f, s2=0.f;
  for (int j=tid;j<C;j+=256){ float v=G[(size_t)i*C+j]; s+=v; s2=fmaf(v,v,s2); }
  __shared__ float r1[4];
  __shared__ float r2[4];
  int lane=tid&63, wv=tid>>6;
  #pragma unroll
  for(int o=32;o;o>>=1){ s+=__shfl_xor(s,o); s2+=__shfl_xor(s2,o); }
  if(lane==0){ r1[wv]=s; r2[wv]=s2; }
  __syncthreads();
  if(tid==0){
    float ss = r1[0]+r1[1]+r1[2]+r1[3];
    float ss2= r2[0]+r2[1]+r2[2]+r2[3];
    float mu = ss/C;
    float var= ss2/C - mu*mu;
    float a  = rsqrtf(var+EPS)*gnw[i];
    alpha[i]=a; beta[i]=gnb[i]-mu*a;
  }
}

__device__ float block_softmax_norm(float v, float* red, int tid){
  int lane=tid&63, wv=tid>>6;
  float m=v;
  #pragma unroll
  for(int o=32;o;o>>=1) m=fmaxf(m,__shfl_xor(m,o));
  if(lane==0) red[wv]=m;
  __syncthreads();
  if(tid==0){ float mm=red[0]; for(int i=1;i<8;i++) mm=fmaxf(mm,red[i]); red[8]=mm; }
  __syncthreads();
  float e=__expf(v-red[8]);
  float su=e;
  #pragma unroll
  for(int o=32;o;o>>=1) su+=__shfl_xor(su,o);
  if(lane==0) red[wv]=su;
  __syncthreads();
  if(tid==0){ float ss=0; for(int i=0;i<8;i++) ss+=red[i]; red[8]=ss; }
  __syncthreads();
  float r = e/red[8];
  __syncthreads();
  return r;
}

__global__ void k5c(const float* __restrict__ G, const float* __restrict__ alpha, const float* __restrict__ beta,
                    const float* __restrict__ chansum, float* __restrict__ x21, float* __restrict__ x31){
  __shared__ float red[9];
  int j = threadIdx.x; // 512
  float t=0.f;
  for (int i=0;i<C;i++) t += alpha[i]*G[(size_t)i*C+j] + beta[i];
  x31[j] = block_softmax_norm(t, red, j);
  float m = chansum[j] * (1.0f/HW);
  x21[j] = block_softmax_norm(m, red, j);
}

// K6: partial weights; x2 recomputed inline
__global__ void k6_wpart(const float* __restrict__ x, const float* __restrict__ x3,
                         const float* __restrict__ sh, const float* __restrict__ sw,
                         const float* __restrict__ x21, const float* __restrict__ x31,
                         float* __restrict__ wpart){
  int s = blockIdx.x*256 + threadIdx.x;
  int h = s/W, w = s - h*W;
  int c0 = blockIdx.y*64;
  float acc=0.f;
  for (int c=c0;c<c0+64;c++){
    float xv = x[(size_t)c*HW + s];
    float x2v = xv * sh[c*H + h] * sw[c*W + w];
    acc = fmaf(x21[c], x3[(size_t)c*HW + s], acc);
    acc = fmaf(x31[c], x2v, acc);
  }
  wpart[(size_t)blockIdx.y*HW + s] = acc;
}

__global__ void k6r(const float* __restrict__ wpart, float* __restrict__ weights){
  int s = blockIdx.x*256 + threadIdx.x;
  float a=0.f;
  #pragma unroll
  for (int z=0;z<8;z++) a += wpart[(size_t)z*HW + s];
  weights[s]=a;
}

__global__ void k7_out(const float* __restrict__ x, const float* __restrict__ weights, float* __restrict__ out){
  int idx = blockIdx.x*256 + threadIdx.x;
  float4 xv = ((const float4*)x)[idx];
  float4 wv = ((const float4*)weights)[idx % (HW/4)];
  float4 o;
  o.x = xv.x * sigmoidf_(wv.x);
  o.y = xv.y * sigmoidf_(wv.y);
  o.z = xv.z * sigmoidf_(wv.z);
  o.w = xv.w * sigmoidf_(wv.w);
  ((float4*)out)[idx] = o;
}

extern "C" void kernel_launch(void* const* d_in, const int* in_sizes, int n_in,
                              void* d_out, int out_size, void* d_ws, size_t ws_size,
                              hipStream_t stream) {
  const float* x   = (const float*)d_in[0];
  const float* w1  = (const float*)d_in[1];
  const float* b1  = (const float*)d_in[2];
  const float* w3  = (const float*)d_in[3];
  const float* b3  = (const float*)d_in[4];
  const float* gnw = (const float*)d_in[5];
  const float* gnb = (const float*)d_in[6];
  float* out = (float*)d_out;
  float* ws  = (float*)d_ws;

  float* xh      = ws + OFF_XH;
  float* xw      = ws + OFF_XW;
  float* sh      = ws + OFF_SH;
  float* sw      = ws + OFF_SW;
  float* cs      = ws + OFF_CS;
  float* alpha   = ws + OFF_ALPHA;
  float* beta    = ws + OFF_BETA;
  float* x21     = ws + OFF_X21;
  float* x31     = ws + OFF_X31;
  float* weights = ws + OFF_WEIGHTS;
  float* G       = ws + OFF_G;
  float* wpart   = ws + OFF_WPART;
  float* x3      = ws + OFF_X3;

  // overlay region R: phase 1 (conv inputs), phase 2 (Bt for gram) — stream order serializes
  unsigned short* xph = (unsigned short*)(ws + OFF_R);
  unsigned short* xpl = xph + (size_t)162*WPAD*C;
  unsigned short* aph = xpl + (size_t)162*WPAD*C;
  unsigned short* apl = aph + (size_t)9*16*4*512*8;
  unsigned short* Bth = (unsigned short*)(ws + OFF_R);
  unsigned short* Btl = Bth + (size_t)HW*C;

  kA_pack <<<(9*16*4*512*8 + 255)/256, 256, 0, stream>>>(w3, aph, apl);
  kB_pad  <<<dim3(162, 8), 256, 0, stream>>>(x, xph, xpl);
  k1_means<<<C, 256, 0, stream>>>(x, xh, xw);
  k2_hwfeat<<<C, 320, 0, stream>>>(w1, b1, xh, xw, sh, sw);
  k3_cs   <<<C, 256, 0, stream>>>(x, sh, sw, cs);
  k4_mfma <<<640, 256, 0, stream>>>(xph, xpl, aph, apl, b3, x3);
  kT_trans<<<dim3(HW/64, C/64), 256, 0, stream>>>(x3, Bth, Btl);
  kz_zero <<<(C*C)/256, 256, 0, stream>>>(G);
  k5g     <<<dim3(4, 4, 16), 256, 0, stream>>>(x3, Bth, Btl, G);
  k5b     <<<C, 256, 0, stream>>>(G, gnw, gnb, alpha, beta);
  k5c     <<<1, 512, 0, stream>>>(G, alpha, beta, cs, x21, x31);
  k6_wpart<<<dim3(HW/256, 8), 256, 0, stream>>>(x, x3, sh, sw, x21, x31, wpart);
  k6r     <<<HW/256, 256, 0, stream>>>(wpart, weights);
  k7_out  <<<(C*HW/4)/256, 256, 0, stream>>>(x, weights, out);
}